// Round 27
// baseline (208.283 us; speedup 1.0000x reference)
//
#include <hip/hip_runtime.h>
#include <stdint.h>

typedef uint16_t u16;
typedef uint32_t u32;
typedef uint64_t u64;

#define CONF_THRESH 0.5f
#define PIOU_THRESH 0.5f
#define NBIN 64      // fixed-width spatial bins (width 79.7; box width < 95 -> edges span <=1 bin)
#define NWAVE 8      // nms waves: wave 0 consumes, waves 1-7 stage
#define CPR 4        // chunks per round (chunks are 128 ranks wide)
#define ECAP_CHUNK 12288 // edge slots per 128-chunk (2x R9's 6144: same margin per rank)
#define ESTG 3584    // edges staged in LDS per chunk (2x R15's 1792: same per-rank capacity)
#define CHW 4096     // u32 per chunk buffer: 512 meta (128 ranks x 4) + 3584 staged edges (16 KB)
#define NBKT 2048    // conf-bit buckets for counting rank
#define BCAP 64      // members per bucket (lambda~4; P(overflow) ~ 1e-60; writes guarded)
#define NSWP 14      // max 256-edge sweeps per chunk (ESTG/256)

// ---------------------------------------------------------------------------
// K1: bucket histogram + member-key lists + aux zeroing (proven R16-R26).
// Multi-block all-CU shape (R20's 1-block variant slowed downstream by ~15us).
// ---------------------------------------------------------------------------
__global__ void __launch_bounds__(256) hist_kernel(
        const float* __restrict__ in, u32* __restrict__ hist, u64* __restrict__ mem,
        u32* __restrict__ meta, u32* __restrict__ echnk, u32* __restrict__ bcnt,
        u16* __restrict__ grankg, int N) {
    int i = blockIdx.x * 256 + threadIdx.x;      // N threads total
    for (int q = i; q < 4 * N; q += N) meta[q] = 0u;
    if (i < 256) echnk[i] = 0u;                  // covers 128 chunks
    if (i < NBIN) bcnt[i] = 0u;
    u32* g32 = (u32*)grankg;
    if (i < N / 2) g32[i] = 0u;                  // grankg = all 0 (empty sentinel)
    if (i >= N) return;
    float c = in[(size_t)i * 5];
    if (c > CONF_THRESH) {
        u32 bits = __float_as_uint(c);
        int b = (int)((bits - 0x3F000000u) >> 12);   // 0..2047 (monotone in conf)
        u32 s = atomicAdd(&hist[b], 1u);
        if (s < BCAP)
            mem[(size_t)b * BCAP + s] = ((u64)bits << 32) | (u64)(0xFFFFFFFFu - (u32)i);
    }
}

// ---------------------------------------------------------------------------
// K2: exact rank from buckets -> scatter (verbatim proven R16-R26).
// ---------------------------------------------------------------------------
__global__ void __launch_bounds__(256) rankscat_kernel(
        const float* __restrict__ in, const u32* __restrict__ hist,
        const u64* __restrict__ mem, float4* __restrict__ sbox,
        u32* __restrict__ bcnt, u16* __restrict__ grankg,
        float4* __restrict__ sboxg, int N) {
    __shared__ u32 h[NBKT];
    __shared__ u32 base[NBKT];
    __shared__ u32 p[256];
    int t = threadIdx.x;
    for (int k = t; k < NBKT; k += 256) h[k] = hist[k];
    __syncthreads();
    u32 hv[8]; u32 seg = 0;
    for (int j = 0; j < 8; ++j) { hv[j] = h[t * 8 + j]; seg += hv[j]; }
    p[t] = seg;
    __syncthreads();
    u32 sp = 0;
    for (int q = t + 1; q < 256; ++q) sp += p[q];    // suffix over segments
    u32 run = sp;
    for (int j = 7; j >= 0; --j) { base[t * 8 + j] = run; run += hv[j]; }
    __syncthreads();

    int i = blockIdx.x * 256 + t;
    float c = in[(size_t)i * 5];
    if (c <= CONF_THRESH) return;                // no syncs follow
    u32 bits = __float_as_uint(c);
    int b = (int)((bits - 0x3F000000u) >> 12);
    u64 my = ((u64)bits << 32) | (u64)(0xFFFFFFFFu - (u32)i);
    int n = min((int)h[b], BCAP);
    const u64* mb = mem + (size_t)b * BCAP;
    int cnt = 0;
    for (int e = 0; e < n; ++e) cnt += (mb[e] > my) ? 1 : 0;
    int r = (int)base[b] + cnt;

    const float* pp = in + (size_t)i * 5;
    float4 bx = make_float4(pp[1], pp[2], pp[3], pp[4]);
    sbox[r] = bx;
    int bin = min(NBIN - 1, max(0, (int)(bx.x * ((float)NBIN / 5100.0f))));
    u32 slot = atomicAdd(&bcnt[bin], 1u);
    if (slot < 256) {
        int g = bin * 256 + (int)slot;
        grankg[g] = (u16)(r + 1);                // r+1 encoding; 0 = empty
        sboxg[g] = bx;
    }
}

// ---------------------------------------------------------------------------
// K3: suppression edges, +-1-bin window (verbatim proven R22/R26). 128-rank
// chunks: in-chunk = (ri>>7)==(rj>>7), mask bit in meta[rj*4 + (ri>>5)&3];
// cross-chunk edge ((ri&127)<<16)|rj into chunk ri>>7's list.
// ---------------------------------------------------------------------------
__global__ void mask_pm1_kernel(const float4* __restrict__ sboxg, const u16* __restrict__ grankg,
                                const u32* __restrict__ bcnt,
                                u32* __restrict__ meta, u32* __restrict__ edges,
                                u32* __restrict__ echnk) {
#pragma clang fp contract(off)
    __shared__ float4 cb[192];
    __shared__ u16 cr[192];
    int b = (int)blockIdx.x, s = (int)blockIdx.y, t = threadIdx.x;
    int w0 = (b - 1) * 256 + s * 192;            // window slice start (gidx)
    if (t < 192) {
        int g = w0 + t;
        bool ok = (g >= 0) && (g < NBIN * 256);
        cr[t] = ok ? grankg[g] : (u16)0;         // 0 = empty sentinel
        cb[t] = ok ? sboxg[g] : make_float4(0.0f, 0.0f, 0.0f, 0.0f);
    }
    __syncthreads();
    int nb = min((int)bcnt[b], 256);
    int l = t;
    if (l >= nb) return;
    int g = b * 256 + l;
    int rj = (int)grankg[g] - 1;                 // filled slot: >= 0
    float4 bj = sboxg[g];
    float areaj = (bj.y - bj.x) * bj.w;
    for (int q = 0; q < 192; ++q) {
        int rie = (int)cr[q];
        if (rie == 0) continue;                  // empty slot
        int ri = rie - 1;
        if (ri >= rj) continue;                  // keeps only higher-conf suppressors
        float4 bi = cb[q];
        float inter_start = fmaxf(bi.x, bj.x);
        float inter_end   = fminf(bi.y, bj.y);
        float inter_len   = fmaxf(inter_end - inter_start, 0.0f);
        float inter_h     = fminf(bi.w, bj.w);
        float inter_area  = inter_len * inter_h;
        float areai       = (bi.y - bi.x) * bi.w;
        float union_area  = areai + areaj - inter_area;
        float iou         = inter_area / union_area;
        float peak_dist   = fabsf(bi.z - bj.z);
        float union_start = fminf(bi.x, bj.x);
        float union_end   = fmaxf(bi.y, bj.y);
        float union_dist  = fabsf(union_end - union_start);
        float piou        = iou - peak_dist / union_dist;
        if (piou > PIOU_THRESH) {
            if ((ri >> 7) == (rj >> 7)) {
                atomicOr(&meta[rj * 4 + ((ri >> 5) & 3)], 1u << (ri & 31));
            } else {
                int c = ri >> 7;
                u32 slot = atomicAdd(&echnk[c], 1u);
                if (slot < ECAP_CHUNK)
                    edges[(size_t)c * ECAP_CHUNK + slot] = ((u32)(ri & 127) << 16) | (u32)rj;
            }
        }
    }
}

// ---------------------------------------------------------------------------
// K4: EXACT greedy NMS, 128-rank chunks (proven R22/R26 structure) + R27
// CHANGE: wave 0 BATCHES the edge-sweep ds_reads (it=1..13) into a fully-
// unrolled register array before processing -- the runtime-bound sweep loop
// was issuing ~10-14 serial ~120cy LDS round-trips per chunk (R19's proven
// batch pattern, applied to the last serial-latency loop). All else verbatim.
// ---------------------------------------------------------------------------
__global__ void __launch_bounds__(NWAVE * 64) nmsout_kernel(
        const u32* __restrict__ bcnt, const u32* __restrict__ meta,
        const u32* __restrict__ edges, const u32* __restrict__ echnk,
        const float4* __restrict__ sbox, float4* __restrict__ out, int N) {
    __shared__ u32 alive[512];                   // 16384 bits, rank space
    __shared__ u32 sbuf[2][CPR][CHW];            // 128 KB double-buffered stage
    __shared__ u32 scnt[2][CPR];                 // staged edge counts
    __shared__ u32 mcnt;
    int tid = threadIdx.x;
    int w = tid >> 6, lane = tid & 63;

    // ---- M = sum over bins of (uncapped) valid counts ----
    if (tid < 64) {
        int lc = (int)bcnt[lane];
        lc += __shfl_xor(lc, 1);  lc += __shfl_xor(lc, 2);
        lc += __shfl_xor(lc, 4);  lc += __shfl_xor(lc, 8);
        lc += __shfl_xor(lc, 16); lc += __shfl_xor(lc, 32);
        if (lane == 0) mcnt = (u32)lc;
    }
    __syncthreads();
    int M = (int)mcnt;
    {
        int lo = tid * 32;
        alive[tid] = (M >= lo + 32) ? 0xFFFFFFFFu : ((M <= lo) ? 0u : ((1u << (M - lo)) - 1u));
    }
    int nchunk = (M + 127) >> 7;                 // 128-rank chunks
    int nround = (nchunk + CPR - 1) / CPR;
    __syncthreads();

#define STAGE(c, pb, k) { \
    int rr = ((c) << 7) + lane; \
    uint4 MT0 = ((const uint4*)meta)[rr]; \
    uint4 MT1 = ((const uint4*)meta)[rr + 64]; \
    u32 ec = echnk[c]; \
    const uint4* eg = (const uint4*)(edges + (size_t)(c) * ECAP_CHUNK); \
    uint4 EB[14]; \
    _Pragma("unroll") \
    for (int q = 0; q < 14; ++q) EB[q] = eg[q * 64 + lane]; \
    u32* sb = &sbuf[pb][k][0]; \
    ((uint4*)sb)[lane] = MT0; \
    ((uint4*)sb)[64 + lane] = MT1; \
    uint4* ed = (uint4*)(sb + 512); \
    _Pragma("unroll") \
    for (int q = 0; q < 14; ++q) ed[q * 64 + lane] = EB[q]; \
    if (lane == 0) scnt[pb][k] = ec; }

#define PROC_E(wd, idx, LIM) { \
    if ((int)(idx) < (LIM)) { \
        u32 sl = (wd) >> 16; u32 tg = (wd) & 0xFFFFu; \
        u64 ksel = (sl & 64) ? kept_hi : kept_lo; \
        if ((ksel >> (sl & 63)) & 1ull) atomicAnd(&alive[tg >> 5], ~(1u << (tg & 31))); } }

    if (nchunk > 0) {
        // prologue: waves 1-4 stage round 0's chunks into buffer 0
        if (w >= 1) {
            for (int k = w - 1; k < CPR; k += 7) {
                if (k < nchunk) STAGE(k, 0, k)
            }
        }
        __syncthreads();

        for (int rd = 0; rd < nround; ++rd) {
            int pb = rd & 1;
            if (w >= 1) {
                // stage round rd+1 into the other buffer
                int b2 = (rd + 1) * CPR;
                for (int k = w - 1; k < CPR; k += 7) {
                    int c = b2 + k;
                    if (c < nchunk) STAGE(c, pb ^ 1, k)
                }
            } else {
                // wave 0: batch-prefetch this round's meta halves / first edges / counts
                int nk = nchunk - rd * CPR; if (nk > CPR) nk = CPR;
                uint4 MT0s[CPR], MT1s[CPR], E0s[CPR]; u32 ECa[CPR];
#pragma unroll
                for (int k = 0; k < CPR; ++k) {
                    if (k < nk) {
                        const u32* sb = &sbuf[pb][k][0];
                        MT0s[k] = ((const uint4*)sb)[lane];
                        MT1s[k] = ((const uint4*)sb)[64 + lane];
                        E0s[k] = ((const uint4*)(sb + 512))[lane];
                        ECa[k] = scnt[pb][k];
                    }
                }
                // process chunks in rank order (alive chain stays serial)
#pragma unroll
                for (int k = 0; k < CPR; ++k) {
                    if (k < nk) {
                        int c = rd * CPR + k;
                        int base = c << 7;
                        const u32* sb = &sbuf[pb][k][0];
                        uint4 MT0 = MT0s[k], MT1 = MT1s[k];
                        int EC = min((int)ECa[k], ECAP_CHUNK);
                        int ECl = min(EC, ESTG);
                        const uint4* ed = (const uint4*)(sb + 512);
                        // R27: batch ALL remaining sweep loads (wave-uniform
                        // guards, compile-time indices) -- independent
                        // ds_reads overlap under one lgkmcnt instead of
                        // ~13 serial 120cy round-trips.
                        uint4 EBt[NSWP];
#pragma unroll
                        for (int it = 1; it < NSWP; ++it)
                            EBt[it] = (it * 256 < ECl) ? ed[it * 64 + lane]
                                                       : make_uint4(0u, 0u, 0u, 0u);

                        u64 av_lo = ((u64)alive[(base >> 5) + 1] << 32) | (u64)alive[base >> 5];
                        u64 av_hi = ((u64)alive[(base >> 5) + 3] << 32) | (u64)alive[(base >> 5) + 2];
                        u64 kept_lo, kept_hi;
                        u32 anym = MT0.x | MT0.y | MT0.z | MT0.w | MT1.x | MT1.y | MT1.z | MT1.w;
                        if (__ballot(anym != 0u) == 0ull) {
                            kept_lo = av_lo; kept_hi = av_hi;    // no in-chunk deps (common)
                        } else {
                            u64 m0_lo = MT0.x | ((u64)MT0.y << 32), m0_hi = MT0.z | ((u64)MT0.w << 32);
                            u64 m1_lo = MT1.x | ((u64)MT1.y << 32), m1_hi = MT1.z | ((u64)MT1.w << 32);
                            u64 undec_lo = av_lo, undec_hi = av_hi;
                            kept_lo = 0ull; kept_hi = 0ull;
                            while (undec_lo | undec_hi) {
                                bool iam0 = (undec_lo >> lane) & 1ull;
                                bool bad0 = ((m0_lo & kept_lo) | (m0_hi & kept_hi)) != 0ull;
                                bool rdy0 = ((m0_lo & undec_lo) | (m0_hi & undec_hi)) == 0ull;
                                bool iam1 = (undec_hi >> lane) & 1ull;
                                bool bad1 = ((m1_lo & kept_lo) | (m1_hi & kept_hi)) != 0ull;
                                bool rdy1 = ((m1_lo & undec_lo) | (m1_hi & undec_hi)) == 0ull;
                                u64 nk_lo = __ballot(iam0 && !bad0 && rdy0);
                                u64 nr_lo = __ballot(iam0 && bad0);
                                u64 nk_hi = __ballot(iam1 && !bad1 && rdy1);
                                u64 nr_hi = __ballot(iam1 && bad1);
                                u64 pl = nk_lo | nr_lo, ph = nk_hi | nr_hi;
                                if ((pl | ph) == 0ull) {         // hang insurance (dead on valid data)
                                    if (undec_lo) { pl = undec_lo & (~undec_lo + 1ull); nk_lo = pl; }
                                    else          { ph = undec_hi & (~undec_hi + 1ull); nk_hi = ph; }
                                }
                                kept_lo |= nk_lo; kept_hi |= nk_hi;
                                undec_lo &= ~pl;  undec_hi &= ~ph;
                            }
                        }
                        if (lane < 4) {
                            u32 word = (lane == 0) ? (u32)kept_lo :
                                       (lane == 1) ? (u32)(kept_lo >> 32) :
                                       (lane == 2) ? (u32)kept_hi : (u32)(kept_hi >> 32);
                            alive[(base >> 5) + lane] = word;
                        }

                        if (ECl > 0) {                       // it = 0 from prefetch
                            uint4 E = E0s[k];
                            int e0 = lane * 4;
                            PROC_E(E.x, e0,     ECl)
                            PROC_E(E.y, e0 + 1, ECl)
                            PROC_E(E.z, e0 + 2, ECl)
                            PROC_E(E.w, e0 + 3, ECl)
                        }
#pragma unroll
                        for (int it = 1; it < NSWP; ++it) {  // batched sweeps
                            if (it * 256 < ECl) {
                                uint4 E = EBt[it];
                                int e0 = it * 256 + lane * 4;
                                PROC_E(E.x, e0,     ECl)
                                PROC_E(E.y, e0 + 1, ECl)
                                PROC_E(E.z, e0 + 2, ECl)
                                PROC_E(E.w, e0 + 3, ECl)
                            }
                        }
                        if (EC > ESTG) {                     // rare coalesced tail
                            const uint4* eg = (const uint4*)(edges + (size_t)c * ECAP_CHUNK);
                            for (int eb = ESTG; eb < EC; eb += 256) {
                                uint4 E = eg[(eb >> 2) + lane];
                                int e0 = eb + lane * 4;
                                PROC_E(E.x, e0,     EC)
                                PROC_E(E.y, e0 + 1, EC)
                                PROC_E(E.z, e0 + 2, EC)
                                PROC_E(E.w, e0 + 3, EC)
                            }
                        }
                    }
                }
            }
            __syncthreads();                     // staging done + buffer handoff
        }
    }

    // fused output: all 8 waves stream the result (alive is final)
    for (int r = tid; r < N; r += NWAVE * 64) {
        if (r < M) {
            float kf = (float)((alive[r >> 5] >> (r & 31)) & 1u);
            float4 v = sbox[r];
            out[r] = make_float4(v.x * kf, v.y * kf, v.z * kf, v.w * kf);
        } else {
            out[r] = make_float4(0.0f, 0.0f, 0.0f, 0.0f);
        }
    }
#undef STAGE
#undef PROC_E
}

// ---------------------------------------------------------------------------
extern "C" void kernel_launch(void* const* d_in, const int* in_sizes, int n_in,
                              void* d_out, int out_size, void* d_ws, size_t ws_size,
                              hipStream_t stream) {
    const float* in = (const float*)d_in[0];
    int N = in_sizes[0] / 5;          // 16384
    int nchunk_max = N / 128;         // 128

    char* ws = (char*)d_ws;
    size_t off = 0;
    u32* hist    = (u32*)(ws + off); off += (size_t)NBKT * 4;         // 8 KB (memset'd)
    u32* bcnt    = (u32*)(ws + off); off += (size_t)NBIN * 4;         // 256 B
    u32* echnk   = (u32*)(ws + off); off += 256 * 4;                  // 1 KB (128 used)
    u16* grankg  = (u16*)(ws + off); off += (size_t)N * 2;            // 32 KB
    off = (off + 15) & ~(size_t)15;
    u32* meta    = (u32*)(ws + off); off += (size_t)N * 16;           // 256 KB
    u64* mem     = (u64*)(ws + off); off += (size_t)NBKT * BCAP * 8;  // 1 MB
    float4* sbox  = (float4*)(ws + off); off += (size_t)N * 16;       // 256 KB
    float4* sboxg = (float4*)(ws + off); off += (size_t)N * 16;       // 256 KB
    u32* edges   = (u32*)(ws + off);  off += (size_t)nchunk_max * ECAP_CHUNK * 4;  // 6 MB

    hipMemsetAsync(hist, 0, (size_t)NBKT * 4, stream);

    hist_kernel<<<N / 256, 256, 0, stream>>>(in, hist, mem, meta, echnk, bcnt, grankg, N);
    rankscat_kernel<<<N / 256, 256, 0, stream>>>(in, hist, mem, sbox, bcnt, grankg, sboxg, N);
    mask_pm1_kernel<<<dim3(NBIN, 4), 256, 0, stream>>>(sboxg, grankg, bcnt, meta, edges, echnk);
    nmsout_kernel<<<1, NWAVE * 64, 0, stream>>>(bcnt, meta, edges, echnk, sbox, (float4*)d_out, N);
}

// Round 28
// 185.646 us; speedup vs baseline: 1.1219x; 1.1219x over previous
//
#include <hip/hip_runtime.h>
#include <stdint.h>

typedef uint16_t u16;
typedef uint32_t u32;
typedef uint64_t u64;

#define CONF_THRESH 0.5f
#define PIOU_THRESH 0.5f
#define NBIN 64      // fixed-width spatial bins (width 79.7; box width < 95 -> edges span <=1 bin)
#define NWAVE 8      // nms waves: wave 0 consumes, waves 1-7 stage
#define CPR 4        // chunks per round (chunks are 128 ranks wide)
#define ECAP_CHUNK 12288 // edge slots per 128-chunk (2x R9's 6144: same margin per rank)
#define ESTG 3584    // edges staged in LDS per chunk (2x R15's 1792: same per-rank capacity)
#define CHW 4096     // u32 per chunk buffer: 512 meta (128 ranks x 4) + 3584 staged edges (16 KB)
#define NBKT 2048    // conf-bit buckets for counting rank
#define BCAP 64      // members per bucket (lambda~4; P(overflow) ~ 1e-60; writes guarded)

// ---------------------------------------------------------------------------
// K1: bucket histogram + member-key lists + aux zeroing (proven R16-R26).
// Multi-block all-CU shape (R20's 1-block variant slowed downstream by ~15us).
// ---------------------------------------------------------------------------
__global__ void __launch_bounds__(256) hist_kernel(
        const float* __restrict__ in, u32* __restrict__ hist, u64* __restrict__ mem,
        u32* __restrict__ meta, u32* __restrict__ echnk, u32* __restrict__ bcnt,
        u16* __restrict__ grankg, int N) {
    int i = blockIdx.x * 256 + threadIdx.x;      // N threads total
    for (int q = i; q < 4 * N; q += N) meta[q] = 0u;
    if (i < 256) echnk[i] = 0u;                  // covers 128 chunks
    if (i < NBIN) bcnt[i] = 0u;
    u32* g32 = (u32*)grankg;
    if (i < N / 2) g32[i] = 0u;                  // grankg = all 0 (empty sentinel)
    if (i >= N) return;
    float c = in[(size_t)i * 5];
    if (c > CONF_THRESH) {
        u32 bits = __float_as_uint(c);
        int b = (int)((bits - 0x3F000000u) >> 12);   // 0..2047 (monotone in conf)
        u32 s = atomicAdd(&hist[b], 1u);
        if (s < BCAP)
            mem[(size_t)b * BCAP + s] = ((u64)bits << 32) | (u64)(0xFFFFFFFFu - (u32)i);
    }
}

// ---------------------------------------------------------------------------
// K2: exact rank from buckets -> scatter (verbatim proven R16-R26).
// ---------------------------------------------------------------------------
__global__ void __launch_bounds__(256) rankscat_kernel(
        const float* __restrict__ in, const u32* __restrict__ hist,
        const u64* __restrict__ mem, float4* __restrict__ sbox,
        u32* __restrict__ bcnt, u16* __restrict__ grankg,
        float4* __restrict__ sboxg, int N) {
    __shared__ u32 h[NBKT];
    __shared__ u32 base[NBKT];
    __shared__ u32 p[256];
    int t = threadIdx.x;
    for (int k = t; k < NBKT; k += 256) h[k] = hist[k];
    __syncthreads();
    u32 hv[8]; u32 seg = 0;
    for (int j = 0; j < 8; ++j) { hv[j] = h[t * 8 + j]; seg += hv[j]; }
    p[t] = seg;
    __syncthreads();
    u32 sp = 0;
    for (int q = t + 1; q < 256; ++q) sp += p[q];    // suffix over segments
    u32 run = sp;
    for (int j = 7; j >= 0; --j) { base[t * 8 + j] = run; run += hv[j]; }
    __syncthreads();

    int i = blockIdx.x * 256 + t;
    float c = in[(size_t)i * 5];
    if (c <= CONF_THRESH) return;                // no syncs follow
    u32 bits = __float_as_uint(c);
    int b = (int)((bits - 0x3F000000u) >> 12);
    u64 my = ((u64)bits << 32) | (u64)(0xFFFFFFFFu - (u32)i);
    int n = min((int)h[b], BCAP);
    const u64* mb = mem + (size_t)b * BCAP;
    int cnt = 0;
    for (int e = 0; e < n; ++e) cnt += (mb[e] > my) ? 1 : 0;
    int r = (int)base[b] + cnt;

    const float* pp = in + (size_t)i * 5;
    float4 bx = make_float4(pp[1], pp[2], pp[3], pp[4]);
    sbox[r] = bx;
    int bin = min(NBIN - 1, max(0, (int)(bx.x * ((float)NBIN / 5100.0f))));
    u32 slot = atomicAdd(&bcnt[bin], 1u);
    if (slot < 256) {
        int g = bin * 256 + (int)slot;
        grankg[g] = (u16)(r + 1);                // r+1 encoding; 0 = empty
        sboxg[g] = bx;
    }
}

// ---------------------------------------------------------------------------
// K3: suppression edges, +-1-bin window (verbatim proven R22/R26). 128-rank
// chunks: in-chunk = (ri>>7)==(rj>>7), mask bit in meta[rj*4 + (ri>>5)&3];
// cross-chunk edge ((ri&127)<<16)|rj into chunk ri>>7's list.
// ---------------------------------------------------------------------------
__global__ void mask_pm1_kernel(const float4* __restrict__ sboxg, const u16* __restrict__ grankg,
                                const u32* __restrict__ bcnt,
                                u32* __restrict__ meta, u32* __restrict__ edges,
                                u32* __restrict__ echnk) {
#pragma clang fp contract(off)
    __shared__ float4 cb[192];
    __shared__ u16 cr[192];
    int b = (int)blockIdx.x, s = (int)blockIdx.y, t = threadIdx.x;
    int w0 = (b - 1) * 256 + s * 192;            // window slice start (gidx)
    if (t < 192) {
        int g = w0 + t;
        bool ok = (g >= 0) && (g < NBIN * 256);
        cr[t] = ok ? grankg[g] : (u16)0;         // 0 = empty sentinel
        cb[t] = ok ? sboxg[g] : make_float4(0.0f, 0.0f, 0.0f, 0.0f);
    }
    __syncthreads();
    int nb = min((int)bcnt[b], 256);
    int l = t;
    if (l >= nb) return;
    int g = b * 256 + l;
    int rj = (int)grankg[g] - 1;                 // filled slot: >= 0
    float4 bj = sboxg[g];
    float areaj = (bj.y - bj.x) * bj.w;
    for (int q = 0; q < 192; ++q) {
        int rie = (int)cr[q];
        if (rie == 0) continue;                  // empty slot
        int ri = rie - 1;
        if (ri >= rj) continue;                  // keeps only higher-conf suppressors
        float4 bi = cb[q];
        float inter_start = fmaxf(bi.x, bj.x);
        float inter_end   = fminf(bi.y, bj.y);
        float inter_len   = fmaxf(inter_end - inter_start, 0.0f);
        float inter_h     = fminf(bi.w, bj.w);
        float inter_area  = inter_len * inter_h;
        float areai       = (bi.y - bi.x) * bi.w;
        float union_area  = areai + areaj - inter_area;
        float iou         = inter_area / union_area;
        float peak_dist   = fabsf(bi.z - bj.z);
        float union_start = fminf(bi.x, bj.x);
        float union_end   = fmaxf(bi.y, bj.y);
        float union_dist  = fabsf(union_end - union_start);
        float piou        = iou - peak_dist / union_dist;
        if (piou > PIOU_THRESH) {
            if ((ri >> 7) == (rj >> 7)) {
                atomicOr(&meta[rj * 4 + ((ri >> 5) & 3)], 1u << (ri & 31));
            } else {
                int c = ri >> 7;
                u32 slot = atomicAdd(&echnk[c], 1u);
                if (slot < ECAP_CHUNK)
                    edges[(size_t)c * ECAP_CHUNK + slot] = ((u32)(ri & 127) << 16) | (u32)rj;
            }
        }
    }
}

// ---------------------------------------------------------------------------
// K4: EXACT greedy NMS with 128-RANK CHUNKS (verbatim proven R22/R26, session
// best): waves 1-7 stage next round's 4 chunks (double-buffered), wave 0
// consumes with batch register prefetch + m==0 fast path; 128-wide ballot
// fixpoint (2 ranks/lane, rare path) + hang-guard; 256-edge cooperative
// sweeps; fused output tail; M = sum of bcnt. No setprio (R17 A/B), no
// sweep-batching (R27: -15us, loads dead slots), no parallel gather
// (R23-25: null-to-negative). This serial structure is the measured floor.
// ---------------------------------------------------------------------------
__global__ void __launch_bounds__(NWAVE * 64) nmsout_kernel(
        const u32* __restrict__ bcnt, const u32* __restrict__ meta,
        const u32* __restrict__ edges, const u32* __restrict__ echnk,
        const float4* __restrict__ sbox, float4* __restrict__ out, int N) {
    __shared__ u32 alive[512];                   // 16384 bits, rank space
    __shared__ u32 sbuf[2][CPR][CHW];            // 128 KB double-buffered stage
    __shared__ u32 scnt[2][CPR];                 // staged edge counts
    __shared__ u32 mcnt;
    int tid = threadIdx.x;
    int w = tid >> 6, lane = tid & 63;

    // ---- M = sum over bins of (uncapped) valid counts ----
    if (tid < 64) {
        int lc = (int)bcnt[lane];
        lc += __shfl_xor(lc, 1);  lc += __shfl_xor(lc, 2);
        lc += __shfl_xor(lc, 4);  lc += __shfl_xor(lc, 8);
        lc += __shfl_xor(lc, 16); lc += __shfl_xor(lc, 32);
        if (lane == 0) mcnt = (u32)lc;
    }
    __syncthreads();
    int M = (int)mcnt;
    {
        int lo = tid * 32;
        alive[tid] = (M >= lo + 32) ? 0xFFFFFFFFu : ((M <= lo) ? 0u : ((1u << (M - lo)) - 1u));
    }
    int nchunk = (M + 127) >> 7;                 // 128-rank chunks
    int nround = (nchunk + CPR - 1) / CPR;
    __syncthreads();

#define STAGE(c, pb, k) { \
    int rr = ((c) << 7) + lane; \
    uint4 MT0 = ((const uint4*)meta)[rr]; \
    uint4 MT1 = ((const uint4*)meta)[rr + 64]; \
    u32 ec = echnk[c]; \
    const uint4* eg = (const uint4*)(edges + (size_t)(c) * ECAP_CHUNK); \
    uint4 EB[14]; \
    _Pragma("unroll") \
    for (int q = 0; q < 14; ++q) EB[q] = eg[q * 64 + lane]; \
    u32* sb = &sbuf[pb][k][0]; \
    ((uint4*)sb)[lane] = MT0; \
    ((uint4*)sb)[64 + lane] = MT1; \
    uint4* ed = (uint4*)(sb + 512); \
    _Pragma("unroll") \
    for (int q = 0; q < 14; ++q) ed[q * 64 + lane] = EB[q]; \
    if (lane == 0) scnt[pb][k] = ec; }

#define PROC_E(wd, idx, LIM) { \
    if ((int)(idx) < (LIM)) { \
        u32 sl = (wd) >> 16; u32 tg = (wd) & 0xFFFFu; \
        u64 ksel = (sl & 64) ? kept_hi : kept_lo; \
        if ((ksel >> (sl & 63)) & 1ull) atomicAnd(&alive[tg >> 5], ~(1u << (tg & 31))); } }

    if (nchunk > 0) {
        // prologue: waves 1-4 stage round 0's chunks into buffer 0
        if (w >= 1) {
            for (int k = w - 1; k < CPR; k += 7) {
                if (k < nchunk) STAGE(k, 0, k)
            }
        }
        __syncthreads();

        for (int rd = 0; rd < nround; ++rd) {
            int pb = rd & 1;
            if (w >= 1) {
                // stage round rd+1 into the other buffer
                int b2 = (rd + 1) * CPR;
                for (int k = w - 1; k < CPR; k += 7) {
                    int c = b2 + k;
                    if (c < nchunk) STAGE(c, pb ^ 1, k)
                }
            } else {
                // wave 0: batch-prefetch this round's meta halves / first edges / counts
                int nk = nchunk - rd * CPR; if (nk > CPR) nk = CPR;
                uint4 MT0s[CPR], MT1s[CPR], E0s[CPR]; u32 ECa[CPR];
#pragma unroll
                for (int k = 0; k < CPR; ++k) {
                    if (k < nk) {
                        const u32* sb = &sbuf[pb][k][0];
                        MT0s[k] = ((const uint4*)sb)[lane];
                        MT1s[k] = ((const uint4*)sb)[64 + lane];
                        E0s[k] = ((const uint4*)(sb + 512))[lane];
                        ECa[k] = scnt[pb][k];
                    }
                }
                // process chunks in rank order (alive chain stays serial)
#pragma unroll
                for (int k = 0; k < CPR; ++k) {
                    if (k < nk) {
                        int c = rd * CPR + k;
                        int base = c << 7;
                        const u32* sb = &sbuf[pb][k][0];
                        uint4 MT0 = MT0s[k], MT1 = MT1s[k];
                        u64 av_lo = ((u64)alive[(base >> 5) + 1] << 32) | (u64)alive[base >> 5];
                        u64 av_hi = ((u64)alive[(base >> 5) + 3] << 32) | (u64)alive[(base >> 5) + 2];
                        u64 kept_lo, kept_hi;
                        u32 anym = MT0.x | MT0.y | MT0.z | MT0.w | MT1.x | MT1.y | MT1.z | MT1.w;
                        if (__ballot(anym != 0u) == 0ull) {
                            kept_lo = av_lo; kept_hi = av_hi;    // no in-chunk deps (common)
                        } else {
                            u64 m0_lo = MT0.x | ((u64)MT0.y << 32), m0_hi = MT0.z | ((u64)MT0.w << 32);
                            u64 m1_lo = MT1.x | ((u64)MT1.y << 32), m1_hi = MT1.z | ((u64)MT1.w << 32);
                            u64 undec_lo = av_lo, undec_hi = av_hi;
                            kept_lo = 0ull; kept_hi = 0ull;
                            while (undec_lo | undec_hi) {
                                bool iam0 = (undec_lo >> lane) & 1ull;
                                bool bad0 = ((m0_lo & kept_lo) | (m0_hi & kept_hi)) != 0ull;
                                bool rdy0 = ((m0_lo & undec_lo) | (m0_hi & undec_hi)) == 0ull;
                                bool iam1 = (undec_hi >> lane) & 1ull;
                                bool bad1 = ((m1_lo & kept_lo) | (m1_hi & kept_hi)) != 0ull;
                                bool rdy1 = ((m1_lo & undec_lo) | (m1_hi & undec_hi)) == 0ull;
                                u64 nk_lo = __ballot(iam0 && !bad0 && rdy0);
                                u64 nr_lo = __ballot(iam0 && bad0);
                                u64 nk_hi = __ballot(iam1 && !bad1 && rdy1);
                                u64 nr_hi = __ballot(iam1 && bad1);
                                u64 pl = nk_lo | nr_lo, ph = nk_hi | nr_hi;
                                if ((pl | ph) == 0ull) {         // hang insurance (dead on valid data)
                                    if (undec_lo) { pl = undec_lo & (~undec_lo + 1ull); nk_lo = pl; }
                                    else          { ph = undec_hi & (~undec_hi + 1ull); nk_hi = ph; }
                                }
                                kept_lo |= nk_lo; kept_hi |= nk_hi;
                                undec_lo &= ~pl;  undec_hi &= ~ph;
                            }
                        }
                        if (lane < 4) {
                            u32 word = (lane == 0) ? (u32)kept_lo :
                                       (lane == 1) ? (u32)(kept_lo >> 32) :
                                       (lane == 2) ? (u32)kept_hi : (u32)(kept_hi >> 32);
                            alive[(base >> 5) + lane] = word;
                        }

                        int EC = min((int)ECa[k], ECAP_CHUNK);
                        int ECl = min(EC, ESTG);
                        const uint4* ed = (const uint4*)(sb + 512);
                        if (ECl > 0) {                       // it = 0 from prefetch
                            uint4 E = E0s[k];
                            int e0 = lane * 4;
                            PROC_E(E.x, e0,     ECl)
                            PROC_E(E.y, e0 + 1, ECl)
                            PROC_E(E.z, e0 + 2, ECl)
                            PROC_E(E.w, e0 + 3, ECl)
                        }
                        for (int it = 1; it * 256 < ECl; ++it) {   // uniform bound
                            uint4 E = ed[it * 64 + lane];
                            int e0 = it * 256 + lane * 4;
                            PROC_E(E.x, e0,     ECl)
                            PROC_E(E.y, e0 + 1, ECl)
                            PROC_E(E.z, e0 + 2, ECl)
                            PROC_E(E.w, e0 + 3, ECl)
                        }
                        if (EC > ESTG) {                     // rare coalesced tail
                            const uint4* eg = (const uint4*)(edges + (size_t)c * ECAP_CHUNK);
                            for (int eb = ESTG; eb < EC; eb += 256) {
                                uint4 E = eg[(eb >> 2) + lane];
                                int e0 = eb + lane * 4;
                                PROC_E(E.x, e0,     EC)
                                PROC_E(E.y, e0 + 1, EC)
                                PROC_E(E.z, e0 + 2, EC)
                                PROC_E(E.w, e0 + 3, EC)
                            }
                        }
                    }
                }
            }
            __syncthreads();                     // staging done + buffer handoff
        }
    }

    // fused output: all 8 waves stream the result (alive is final)
    for (int r = tid; r < N; r += NWAVE * 64) {
        if (r < M) {
            float kf = (float)((alive[r >> 5] >> (r & 31)) & 1u);
            float4 v = sbox[r];
            out[r] = make_float4(v.x * kf, v.y * kf, v.z * kf, v.w * kf);
        } else {
            out[r] = make_float4(0.0f, 0.0f, 0.0f, 0.0f);
        }
    }
#undef STAGE
#undef PROC_E
}

// ---------------------------------------------------------------------------
extern "C" void kernel_launch(void* const* d_in, const int* in_sizes, int n_in,
                              void* d_out, int out_size, void* d_ws, size_t ws_size,
                              hipStream_t stream) {
    const float* in = (const float*)d_in[0];
    int N = in_sizes[0] / 5;          // 16384
    int nchunk_max = N / 128;         // 128

    char* ws = (char*)d_ws;
    size_t off = 0;
    u32* hist    = (u32*)(ws + off); off += (size_t)NBKT * 4;         // 8 KB (memset'd)
    u32* bcnt    = (u32*)(ws + off); off += (size_t)NBIN * 4;         // 256 B
    u32* echnk   = (u32*)(ws + off); off += 256 * 4;                  // 1 KB (128 used)
    u16* grankg  = (u16*)(ws + off); off += (size_t)N * 2;            // 32 KB
    off = (off + 15) & ~(size_t)15;
    u32* meta    = (u32*)(ws + off); off += (size_t)N * 16;           // 256 KB
    u64* mem     = (u64*)(ws + off); off += (size_t)NBKT * BCAP * 8;  // 1 MB
    float4* sbox  = (float4*)(ws + off); off += (size_t)N * 16;       // 256 KB
    float4* sboxg = (float4*)(ws + off); off += (size_t)N * 16;       // 256 KB
    u32* edges   = (u32*)(ws + off);  off += (size_t)nchunk_max * ECAP_CHUNK * 4;  // 6 MB

    hipMemsetAsync(hist, 0, (size_t)NBKT * 4, stream);

    hist_kernel<<<N / 256, 256, 0, stream>>>(in, hist, mem, meta, echnk, bcnt, grankg, N);
    rankscat_kernel<<<N / 256, 256, 0, stream>>>(in, hist, mem, sbox, bcnt, grankg, sboxg, N);
    mask_pm1_kernel<<<dim3(NBIN, 4), 256, 0, stream>>>(sboxg, grankg, bcnt, meta, edges, echnk);
    nmsout_kernel<<<1, NWAVE * 64, 0, stream>>>(bcnt, meta, edges, echnk, sbox, (float4*)d_out, N);
}